// Round 6
// baseline (260.105 us; speedup 1.0000x reference)
//
#include <hip/hip_runtime.h>
#include <stdint.h>

// ---------------------------------------------------------------------------
// TripletRankingLoss — bit-exact JAX replication (absmax 0.0 R1/R3/R4/R5,
// jax_threefry_partitionable=True scheme).
//
// R6: argmax is issue-bound at realistic VALU rates; cut instructions and
// remove VMEM from the hot loop:
//   - NEG phase (93% of work): natural j-sweep 0..8191 (no perm, no tails:
//     8192%256==0), own-group mask via LDS label BYTES (ds_read_u8, DS pipe
//     co-issues with VALU), x1 counter advanced by literal adds. Strict-> is
//     exact (ascending j per lane); cross-lane ties via packed u64 reduce.
//   - POS phase: perm walk of own group (ascending j within group -> strict->).
//   - sort fused into norms kernel (block 0) to save one launch.
// Draw words bit-identical to R1-R5.
// ---------------------------------------------------------------------------

#define B_ROWS 8192
#define DIMS   512
#define NLAB   16   // labels 0..13, padded

__device__ __forceinline__ uint32_t rotl(uint32_t x, uint32_t r) {
  return __builtin_amdgcn_alignbit(x, x, 32u - r);  // rotr(x,32-r) == rotl(x,r)
}

// ---- compile-time threefry block for key derivation (pure literals) -------
struct KeyPair { uint32_t a, b; };
constexpr KeyPair tf_c(uint32_t k0, uint32_t k1, uint32_t x0, uint32_t x1) {
  const uint32_t ks2 = k0 ^ k1 ^ 0x1BD11BDAu;
  x0 += k0; x1 += k1;
#define TFRC(r) { x0 += x1; x1 = (uint32_t)((x1 << (r)) | (x1 >> (32 - (r)))); x1 ^= x0; }
  TFRC(13) TFRC(15) TFRC(26) TFRC(6)
  x0 += k1;  x1 += ks2 + 1u;
  TFRC(17) TFRC(29) TFRC(16) TFRC(24)
  x0 += ks2; x1 += k0 + 2u;
  TFRC(13) TFRC(15) TFRC(26) TFRC(6)
  x0 += k0;  x1 += k1 + 3u;
  TFRC(17) TFRC(29) TFRC(16) TFRC(24)
  x0 += k1;  x1 += ks2 + 4u;
  TFRC(13) TFRC(15) TFRC(26) TFRC(6)
  x0 += ks2; x1 += k0 + 5u;
#undef TFRC
  return {x0, x1};
}
constexpr KeyPair KP = tf_c(0u, 42u, 0u, 0u);  // g_pos keys
constexpr KeyPair KN = tf_c(0u, 42u, 0u, 1u);  // g_neg keys

// ---- runtime draw, keys as literals; injections fused (68 VALU static) ----
template <uint32_t K0, uint32_t K1>
__device__ __forceinline__ uint32_t tf_draw(uint32_t x1) {
  constexpr uint32_t KS2 = K0 ^ K1 ^ 0x1BD11BDAu;
  uint32_t x0 = K0 + x1;
  x1 = rotl(x1, 13); x1 ^= x0;
  x0 += x1; x1 = rotl(x1, 15); x1 ^= x0;
  x0 += x1; x1 = rotl(x1, 26); x1 ^= x0;
  x0 += x1; x1 = rotl(x1, 6);  x1 ^= x0;
  x1 += KS2 + 1u;  x0 = x0 + x1 + K1;
  x1 = rotl(x1, 17); x1 ^= x0;
  x0 += x1; x1 = rotl(x1, 29); x1 ^= x0;
  x0 += x1; x1 = rotl(x1, 16); x1 ^= x0;
  x0 += x1; x1 = rotl(x1, 24); x1 ^= x0;
  x1 += K0 + 2u;   x0 = x0 + x1 + KS2;
  x1 = rotl(x1, 13); x1 ^= x0;
  x0 += x1; x1 = rotl(x1, 15); x1 ^= x0;
  x0 += x1; x1 = rotl(x1, 26); x1 ^= x0;
  x0 += x1; x1 = rotl(x1, 6);  x1 ^= x0;
  x1 += K1 + 3u;   x0 = x0 + x1 + K0;
  x1 = rotl(x1, 17); x1 ^= x0;
  x0 += x1; x1 = rotl(x1, 29); x1 ^= x0;
  x0 += x1; x1 = rotl(x1, 16); x1 ^= x0;
  x0 += x1; x1 = rotl(x1, 24); x1 ^= x0;
  x1 += KS2 + 4u;  x0 = x0 + x1 + K1;
  x1 = rotl(x1, 13); x1 ^= x0;
  x0 += x1; x1 = rotl(x1, 15); x1 ^= x0;
  x0 += x1; x1 = rotl(x1, 26); x1 ^= x0;
  x0 += x1; x1 = rotl(x1, 6);  x1 ^= x0;
  return (x0 + KS2) ^ (x1 + K0 + 5u);
}

// ------------ kernel 1: row norms + (block 0) label counting sort ----------
__global__ __launch_bounds__(256) void norms_sort_kernel(const float* __restrict__ pred,
                                                         const int* __restrict__ labels,
                                                         float* __restrict__ norms,
                                                         int* __restrict__ perm,
                                                         int* __restrict__ gstart) {
  __shared__ int cnt[NLAB][256];
  __shared__ int gs[NLAB + 1];
  // ---- norms for this block's 4 rows ----
  const int wave = threadIdx.x >> 6, lane = threadIdx.x & 63;
  const int r = blockIdx.x * 4 + wave;
  const float4* A = (const float4*)(pred + (size_t)r * DIMS);
  float s = 0.f;
#pragma unroll
  for (int t = 0; t < 2; ++t) {
    const float4 a = A[lane + 64 * t];
    s += a.x * a.x + a.y * a.y + a.z * a.z + a.w * a.w;
  }
  for (int o = 32; o > 0; o >>= 1) s += __shfl_down(s, o, 64);
  if (lane == 0) norms[r] = sqrtf(s);

  // ---- block 0: stable counting sort of [0,8192) by label ----
  if (blockIdx.x != 0) return;
  const int t = threadIdx.x;
  for (int l = 0; l < NLAB; ++l) cnt[l][t] = 0;
  __syncthreads();
  const int base = t * 32;
  for (int e = base; e < base + 32; ++e) cnt[labels[e]][t]++;
  __syncthreads();
  if (t < NLAB) {
    int run = 0;
    for (int k = 0; k < 256; ++k) { const int c = cnt[t][k]; cnt[t][k] = run; run += c; }
    gs[t + 1] = run;
  }
  __syncthreads();
  if (t == 0) {
    gs[0] = 0;
    for (int l = 1; l <= NLAB; ++l) gs[l] += gs[l - 1];
  }
  __syncthreads();
  for (int e = base; e < base + 32; ++e) {
    const int l = labels[e];
    perm[gs[l] + cnt[l][t]++] = e;
  }
  if (t <= NLAB) gstart[t] = gs[t];
}

// ------------- kernel 2: gumbel argmax, one wave per row -------------------
__global__ __launch_bounds__(256) void argmax_kernel(const int* __restrict__ labels,
                                                     const int* __restrict__ perm,
                                                     const int* __restrict__ gstart,
                                                     int* __restrict__ idxp,
                                                     int* __restrict__ idxn) {
  __shared__ uint32_t labw[B_ROWS / 4];  // 8192 label bytes, packed 4/word
  const int tid = threadIdx.x;
  // ---- stage labels as bytes into LDS (thread t packs js [32t, 32t+32)) ----
  {
    const int4* L4 = (const int4*)labels;
#pragma unroll
    for (int q = 0; q < 8; ++q) {
      const int4 a = L4[tid * 8 + q];
      labw[tid * 8 + q] = (uint32_t)a.x | ((uint32_t)a.y << 8) |
                          ((uint32_t)a.z << 16) | ((uint32_t)a.w << 24);
    }
  }
  const int lane = tid & 63;
  const int r = blockIdx.x * 4 + (tid >> 6);
  const int li = __builtin_amdgcn_readfirstlane(labels[r]);
  const int g0 = __builtin_amdgcn_readfirstlane(gstart[li]);
  const int g1 = __builtin_amdgcn_readfirstlane(gstart[li + 1]);
  const uint32_t base = (uint32_t)r << 13;  // r * 8192

  // ---- positive phase: own group via perm (ascending j per lane) ----
  int bv = -1, bj = 0;
  {
    const uint32_t sb = base + KP.b;
    for (int t = g0 + lane; t < g1; t += 64) {
      const int j = perm[t];
      const uint32_t w = tf_draw<KP.a, KP.b>(sb + (uint32_t)j);
      const int v = (int)(w >> 9);  // 23-bit draw; gumbel monotonic in this
      const bool upd = v > bv;      // strict > over ascending j = first index
      bv = upd ? v : bv;
      bj = upd ? j : bj;
    }
  }
  unsigned long long pp =
      (((unsigned long long)(bv + 1)) << 13) | (unsigned)(8191 - bj);

  __syncthreads();  // label bytes visible

  // ---- negative phase: natural sweep j = lane + 64*it, LDS byte mask ----
  bv = -1; bj = 0;
  {
    const uint8_t* lb = (const uint8_t*)labw;
    uint32_t x1w = base + KN.b + (uint32_t)lane;  // counter for j = lane
    int jw = lane;
#pragma unroll 1
    for (int it = 0; it < 128; it += 8) {
#pragma unroll
      for (int u = 0; u < 8; ++u) {
        const uint32_t w = tf_draw<KN.a, KN.b>(x1w + 64u * u);
        const int lab = (int)lb[jw + 64 * u];  // ds_read_u8, imm offset
        const int v = (int)(w >> 9);
        const bool upd = (lab != li) & (v > bv);  // own group masked out
        bv = upd ? v : bv;
        bj = upd ? (jw + 64 * u) : bj;
      }
      x1w += 512u; jw += 512;
    }
  }
  unsigned long long pn =
      (((unsigned long long)(bv + 1)) << 13) | (unsigned)(8191 - bj);

  // ---- wave reduce: max value, tie -> min index (packed) ----
  for (int o = 32; o > 0; o >>= 1) {
    const unsigned long long t1 = __shfl_down(pp, o, 64); if (t1 > pp) pp = t1;
    const unsigned long long t2 = __shfl_down(pn, o, 64); if (t2 > pn) pn = t2;
  }
  if (lane == 0) {
    idxp[r] = 8191 - (int)(pp & 8191ull);
    idxn[r] = 8191 - (int)(pn & 8191ull);
  }
}

// --------------- kernel 3: per-row cosine margin, relu -> cosv -------------
__global__ __launch_bounds__(256) void cos_kernel(const float* __restrict__ pred,
                                                  const float* __restrict__ norms,
                                                  const int* __restrict__ idxp,
                                                  const int* __restrict__ idxn,
                                                  float* __restrict__ cosv) {
  const int wave = threadIdx.x >> 6, lane = threadIdx.x & 63;
  const int r = blockIdx.x * 4 + wave;
  const int ip = idxp[r], inn = idxn[r];
  const float4* A = (const float4*)(pred + (size_t)r * DIMS);
  const float4* P = (const float4*)(pred + (size_t)ip * DIMS);
  const float4* Nn = (const float4*)(pred + (size_t)inn * DIMS);
  float dp = 0.f, dn = 0.f;
#pragma unroll
  for (int t = 0; t < 2; ++t) {
    const float4 a = A[lane + 64 * t];
    const float4 p = P[lane + 64 * t];
    const float4 n = Nn[lane + 64 * t];
    dp += a.x * p.x + a.y * p.y + a.z * p.z + a.w * p.w;
    dn += a.x * n.x + a.y * n.y + a.z * n.z + a.w * n.w;
  }
  for (int o = 32; o > 0; o >>= 1) {
    dp += __shfl_down(dp, o, 64);
    dn += __shfl_down(dn, o, 64);
  }
  if (lane == 0) {
    const float na = fmaxf(norms[r], 1e-6f);
    const float np = fmaxf(norms[ip], 1e-6f);
    const float nn = fmaxf(norms[inn], 1e-6f);
    const float c = dp / (na * np) - dn / (na * nn) + 0.1f;
    cosv[r] = fmaxf(c, 0.f);
  }
}

// --------------------- kernel 4: mean (double accumulate) ------------------
__global__ __launch_bounds__(256) void reduce_kernel(const float* __restrict__ cosv,
                                                     float* __restrict__ out) {
  __shared__ double sh[4];
  double s = 0.0;
  for (int j = threadIdx.x; j < B_ROWS; j += 256) s += (double)cosv[j];
  for (int o = 32; o > 0; o >>= 1) s += __shfl_down(s, o, 64);
  const int wave = threadIdx.x >> 6, lane = threadIdx.x & 63;
  if (lane == 0) sh[wave] = s;
  __syncthreads();
  if (threadIdx.x == 0) {
    const double t = sh[0] + sh[1] + sh[2] + sh[3];
    out[0] = (float)(t / (double)B_ROWS);
  }
}

extern "C" void kernel_launch(void* const* d_in, const int* in_sizes, int n_in,
                              void* d_out, int out_size, void* d_ws, size_t ws_size,
                              hipStream_t stream) {
  const float* pred  = (const float*)d_in[0];
  const int* labels  = (const int*)d_in[1];
  float* out = (float*)d_out;

  char* ws = (char*)d_ws;
  float* norms  = (float*)(ws + 0);
  int*   idxp   = (int*)(ws + 32 * 1024);
  int*   idxn   = (int*)(ws + 64 * 1024);
  float* cosv   = (float*)(ws + 96 * 1024);
  int*   perm   = (int*)(ws + 128 * 1024);
  int*   gstart = (int*)(ws + 160 * 1024);

  norms_sort_kernel<<<B_ROWS / 4, 256, 0, stream>>>(pred, labels, norms, perm, gstart);
  argmax_kernel<<<B_ROWS / 4, 256, 0, stream>>>(labels, perm, gstart, idxp, idxn);
  cos_kernel<<<B_ROWS / 4, 256, 0, stream>>>(pred, norms, idxp, idxn, cosv);
  reduce_kernel<<<1, 256, 0, stream>>>(cosv, out);
}

// Round 7
// 256.723 us; speedup vs baseline: 1.0132x; 1.0132x over previous
//
#include <hip/hip_runtime.h>
#include <stdint.h>

// ---------------------------------------------------------------------------
// TripletRankingLoss — bit-exact JAX replication (absmax 0.0 R1/R3-R6,
// jax_threefry_partitionable=True scheme).
//
// R7: real VALU issue occupancy is ~45% (gfx94x VALUBusy formula overstates
// 2x on SIMD-32): the serial threefry chain leaves issue bubbles. Fix with
// cross-row ILP=2: each wave handles TWO rows (r, r+4); both neg sweeps share
// key KN and the same natural j sequence -> ONE labels[j] load feeds both
// rows, and the two cipher chains are interleaved INSTRUCTION-BY-INSTRUCTION
// in source (paired rounds) so the compiler cannot serialize them (R5's
// array-of-chains attempt was serialized, VGPR=20).
//   - neg: natural j sweep, strict-> (ascending j per lane, no ties), global
//     label dwords (L1-hot, consumed ~560 insts after issue). No LDS (R6
//     regression), no perm, no seam cndmask.
//   - pos: R5's perm-walk per row (7% of work), sequential for the 2 rows.
// Draw words bit-identical to R1-R6.
// ---------------------------------------------------------------------------

#define B_ROWS 8192
#define DIMS   512
#define NLAB   16   // labels 0..13, padded

__device__ __forceinline__ uint32_t rotl(uint32_t x, uint32_t r) {
  return __builtin_amdgcn_alignbit(x, x, 32u - r);  // rotr(x,32-r) == rotl(x,r)
}

// ---- compile-time threefry block for key derivation (pure literals) -------
struct KeyPair { uint32_t a, b; };
constexpr KeyPair tf_c(uint32_t k0, uint32_t k1, uint32_t x0, uint32_t x1) {
  const uint32_t ks2 = k0 ^ k1 ^ 0x1BD11BDAu;
  x0 += k0; x1 += k1;
#define TFRC(r) { x0 += x1; x1 = (uint32_t)((x1 << (r)) | (x1 >> (32 - (r)))); x1 ^= x0; }
  TFRC(13) TFRC(15) TFRC(26) TFRC(6)
  x0 += k1;  x1 += ks2 + 1u;
  TFRC(17) TFRC(29) TFRC(16) TFRC(24)
  x0 += ks2; x1 += k0 + 2u;
  TFRC(13) TFRC(15) TFRC(26) TFRC(6)
  x0 += k0;  x1 += k1 + 3u;
  TFRC(17) TFRC(29) TFRC(16) TFRC(24)
  x0 += k1;  x1 += ks2 + 4u;
  TFRC(13) TFRC(15) TFRC(26) TFRC(6)
  x0 += ks2; x1 += k0 + 5u;
#undef TFRC
  return {x0, x1};
}
constexpr KeyPair KP = tf_c(0u, 42u, 0u, 0u);  // g_pos keys
constexpr KeyPair KN = tf_c(0u, 42u, 0u, 1u);  // g_neg keys

// ---- single-chain draw (pos phase) ----------------------------------------
template <uint32_t K0, uint32_t K1>
__device__ __forceinline__ uint32_t tf_draw(uint32_t x1) {
  constexpr uint32_t KS2 = K0 ^ K1 ^ 0x1BD11BDAu;
  uint32_t x0 = K0 + x1;
  x1 = rotl(x1, 13); x1 ^= x0;
  x0 += x1; x1 = rotl(x1, 15); x1 ^= x0;
  x0 += x1; x1 = rotl(x1, 26); x1 ^= x0;
  x0 += x1; x1 = rotl(x1, 6);  x1 ^= x0;
  x1 += KS2 + 1u;  x0 = x0 + x1 + K1;
  x1 = rotl(x1, 17); x1 ^= x0;
  x0 += x1; x1 = rotl(x1, 29); x1 ^= x0;
  x0 += x1; x1 = rotl(x1, 16); x1 ^= x0;
  x0 += x1; x1 = rotl(x1, 24); x1 ^= x0;
  x1 += K0 + 2u;   x0 = x0 + x1 + KS2;
  x1 = rotl(x1, 13); x1 ^= x0;
  x0 += x1; x1 = rotl(x1, 15); x1 ^= x0;
  x0 += x1; x1 = rotl(x1, 26); x1 ^= x0;
  x0 += x1; x1 = rotl(x1, 6);  x1 ^= x0;
  x1 += K1 + 3u;   x0 = x0 + x1 + K0;
  x1 = rotl(x1, 17); x1 ^= x0;
  x0 += x1; x1 = rotl(x1, 29); x1 ^= x0;
  x0 += x1; x1 = rotl(x1, 16); x1 ^= x0;
  x0 += x1; x1 = rotl(x1, 24); x1 ^= x0;
  x1 += KS2 + 4u;  x0 = x0 + x1 + K1;
  x1 = rotl(x1, 13); x1 ^= x0;
  x0 += x1; x1 = rotl(x1, 15); x1 ^= x0;
  x0 += x1; x1 = rotl(x1, 26); x1 ^= x0;
  x0 += x1; x1 = rotl(x1, 6);  x1 ^= x0;
  return (x0 + KS2) ^ (x1 + K0 + 5u);
}

// ---- dual-chain draw, key KN, rounds interleaved pairwise (ILP=2) ---------
__device__ __forceinline__ void tf_draw2_kn(uint32_t xa1, uint32_t xb1,
                                            uint32_t& wa, uint32_t& wb) {
  constexpr uint32_t K0 = KN.a, K1 = KN.b;
  constexpr uint32_t KS2 = K0 ^ K1 ^ 0x1BD11BDAu;
  uint32_t xa0 = K0 + xa1;            uint32_t xb0 = K0 + xb1;
  xa1 = rotl(xa1, 13);                xb1 = rotl(xb1, 13);
  xa1 ^= xa0;                         xb1 ^= xb0;
#define DR(rr) { xa0 += xa1; xb0 += xb1; \
                 xa1 = rotl(xa1, rr); xb1 = rotl(xb1, rr); \
                 xa1 ^= xa0; xb1 ^= xb0; }
  DR(15) DR(26) DR(6)
  xa1 += KS2 + 1u; xb1 += KS2 + 1u;
  xa0 = xa0 + xa1 + K1;               xb0 = xb0 + xb1 + K1;
  xa1 = rotl(xa1, 17); xa1 ^= xa0;    xb1 = rotl(xb1, 17); xb1 ^= xb0;
  DR(29) DR(16) DR(24)
  xa1 += K0 + 2u;  xb1 += K0 + 2u;
  xa0 = xa0 + xa1 + KS2;              xb0 = xb0 + xb1 + KS2;
  xa1 = rotl(xa1, 13); xa1 ^= xa0;    xb1 = rotl(xb1, 13); xb1 ^= xb0;
  DR(15) DR(26) DR(6)
  xa1 += K1 + 3u;  xb1 += K1 + 3u;
  xa0 = xa0 + xa1 + K0;               xb0 = xb0 + xb1 + K0;
  xa1 = rotl(xa1, 17); xa1 ^= xa0;    xb1 = rotl(xb1, 17); xb1 ^= xb0;
  DR(29) DR(16) DR(24)
  xa1 += KS2 + 4u; xb1 += KS2 + 4u;
  xa0 = xa0 + xa1 + K1;               xb0 = xb0 + xb1 + K1;
  xa1 = rotl(xa1, 13); xa1 ^= xa0;    xb1 = rotl(xb1, 13); xb1 ^= xb0;
  DR(15) DR(26) DR(6)
#undef DR
  wa = (xa0 + KS2) ^ (xa1 + K0 + 5u);
  wb = (xb0 + KS2) ^ (xb1 + K0 + 5u);
}

// ------------ kernel 1: row norms + (block 0) label counting sort ----------
__global__ __launch_bounds__(256) void norms_sort_kernel(const float* __restrict__ pred,
                                                         const int* __restrict__ labels,
                                                         float* __restrict__ norms,
                                                         int* __restrict__ perm,
                                                         int* __restrict__ gstart) {
  __shared__ int cnt[NLAB][256];
  __shared__ int gs[NLAB + 1];
  const int wave = threadIdx.x >> 6, lane = threadIdx.x & 63;
  const int r = blockIdx.x * 4 + wave;
  const float4* A = (const float4*)(pred + (size_t)r * DIMS);
  float s = 0.f;
#pragma unroll
  for (int t = 0; t < 2; ++t) {
    const float4 a = A[lane + 64 * t];
    s += a.x * a.x + a.y * a.y + a.z * a.z + a.w * a.w;
  }
  for (int o = 32; o > 0; o >>= 1) s += __shfl_down(s, o, 64);
  if (lane == 0) norms[r] = sqrtf(s);

  if (blockIdx.x != 0) return;
  const int t = threadIdx.x;
  for (int l = 0; l < NLAB; ++l) cnt[l][t] = 0;
  __syncthreads();
  const int base = t * 32;
  for (int e = base; e < base + 32; ++e) cnt[labels[e]][t]++;
  __syncthreads();
  if (t < NLAB) {
    int run = 0;
    for (int k = 0; k < 256; ++k) { const int c = cnt[t][k]; cnt[t][k] = run; run += c; }
    gs[t + 1] = run;
  }
  __syncthreads();
  if (t == 0) {
    gs[0] = 0;
    for (int l = 1; l <= NLAB; ++l) gs[l] += gs[l - 1];
  }
  __syncthreads();
  for (int e = base; e < base + 32; ++e) {
    const int l = labels[e];
    perm[gs[l] + cnt[l][t]++] = e;
  }
  if (t <= NLAB) gstart[t] = gs[t];
}

// ------- kernel 2: gumbel argmax, one wave per TWO rows (ILP=2 neg) --------
__global__ __launch_bounds__(256) void argmax_kernel(const int* __restrict__ labels,
                                                     const int* __restrict__ perm,
                                                     const int* __restrict__ gstart,
                                                     int* __restrict__ idxp,
                                                     int* __restrict__ idxn) {
  const int lane = threadIdx.x & 63;
  const int wave = threadIdx.x >> 6;
  const int rA = blockIdx.x * 8 + wave;      // rows rA and rB = rA + 4
  const int rB = rA + 4;
  const int liA = __builtin_amdgcn_readfirstlane(labels[rA]);
  const int liB = __builtin_amdgcn_readfirstlane(labels[rB]);

  // ---- positive phase (perm walk, strict >, per row) ----
  unsigned long long ppA, ppB;
  {
    const int g0 = __builtin_amdgcn_readfirstlane(gstart[liA]);
    const int g1 = __builtin_amdgcn_readfirstlane(gstart[liA + 1]);
    const uint32_t sb = ((uint32_t)rA << 13) + KP.b;
    int bv = -1, bj = 0;
    for (int t = g0 + lane; t < g1; t += 64) {
      const int j = perm[t];
      const int v = (int)(tf_draw<KP.a, KP.b>(sb + (uint32_t)j) >> 9);
      const bool upd = v > bv;
      bv = upd ? v : bv;
      bj = upd ? j : bj;
    }
    ppA = (((unsigned long long)(bv + 1)) << 13) | (unsigned)(8191 - bj);
  }
  {
    const int g0 = __builtin_amdgcn_readfirstlane(gstart[liB]);
    const int g1 = __builtin_amdgcn_readfirstlane(gstart[liB + 1]);
    const uint32_t sb = ((uint32_t)rB << 13) + KP.b;
    int bv = -1, bj = 0;
    for (int t = g0 + lane; t < g1; t += 64) {
      const int j = perm[t];
      const int v = (int)(tf_draw<KP.a, KP.b>(sb + (uint32_t)j) >> 9);
      const bool upd = v > bv;
      bv = upd ? v : bv;
      bj = upd ? j : bj;
    }
    ppB = (((unsigned long long)(bv + 1)) << 13) | (unsigned)(8191 - bj);
  }

  // ---- negative phase: shared natural j sweep, dual interleaved chains ----
  int bvA = -1, bjA = 0, bvB = -1, bjB = 0;
  {
    const uint32_t sbA = ((uint32_t)rA << 13) + KN.b;
    const uint32_t sbB = ((uint32_t)rB << 13) + KN.b;
    int jb = lane;
#pragma unroll 1
    for (int it = 0; it < 32; ++it) {
      int lab[4];
#pragma unroll
      for (int u = 0; u < 4; ++u) lab[u] = labels[jb + 64 * u];  // shared loads
#pragma unroll
      for (int u = 0; u < 4; ++u) {
        const uint32_t t1 = (uint32_t)(jb + 64 * u);
        uint32_t wa, wb;
        tf_draw2_kn(t1 + sbA, t1 + sbB, wa, wb);
        const int va = (int)(wa >> 9), vb = (int)(wb >> 9);
        const bool uA = (lab[u] != liA) & (va > bvA);  // ascending j: strict >
        bvA = uA ? va : bvA;
        bjA = uA ? (jb + 64 * u) : bjA;
        const bool uB = (lab[u] != liB) & (vb > bvB);
        bvB = uB ? vb : bvB;
        bjB = uB ? (jb + 64 * u) : bjB;
      }
      jb += 256;
    }
  }
  unsigned long long pnA =
      (((unsigned long long)(bvA + 1)) << 13) | (unsigned)(8191 - bjA);
  unsigned long long pnB =
      (((unsigned long long)(bvB + 1)) << 13) | (unsigned)(8191 - bjB);

  // ---- wave reduce: max value, tie -> min index (packed) ----
  for (int o = 32; o > 0; o >>= 1) {
    unsigned long long t;
    t = __shfl_down(ppA, o, 64); if (t > ppA) ppA = t;
    t = __shfl_down(pnA, o, 64); if (t > pnA) pnA = t;
    t = __shfl_down(ppB, o, 64); if (t > ppB) ppB = t;
    t = __shfl_down(pnB, o, 64); if (t > pnB) pnB = t;
  }
  if (lane == 0) {
    idxp[rA] = 8191 - (int)(ppA & 8191ull);
    idxn[rA] = 8191 - (int)(pnA & 8191ull);
    idxp[rB] = 8191 - (int)(ppB & 8191ull);
    idxn[rB] = 8191 - (int)(pnB & 8191ull);
  }
}

// --------------- kernel 3: per-row cosine margin, relu -> cosv -------------
__global__ __launch_bounds__(256) void cos_kernel(const float* __restrict__ pred,
                                                  const float* __restrict__ norms,
                                                  const int* __restrict__ idxp,
                                                  const int* __restrict__ idxn,
                                                  float* __restrict__ cosv) {
  const int wave = threadIdx.x >> 6, lane = threadIdx.x & 63;
  const int r = blockIdx.x * 4 + wave;
  const int ip = idxp[r], inn = idxn[r];
  const float4* A = (const float4*)(pred + (size_t)r * DIMS);
  const float4* P = (const float4*)(pred + (size_t)ip * DIMS);
  const float4* Nn = (const float4*)(pred + (size_t)inn * DIMS);
  float dp = 0.f, dn = 0.f;
#pragma unroll
  for (int t = 0; t < 2; ++t) {
    const float4 a = A[lane + 64 * t];
    const float4 p = P[lane + 64 * t];
    const float4 n = Nn[lane + 64 * t];
    dp += a.x * p.x + a.y * p.y + a.z * p.z + a.w * p.w;
    dn += a.x * n.x + a.y * n.y + a.z * n.z + a.w * n.w;
  }
  for (int o = 32; o > 0; o >>= 1) {
    dp += __shfl_down(dp, o, 64);
    dn += __shfl_down(dn, o, 64);
  }
  if (lane == 0) {
    const float na = fmaxf(norms[r], 1e-6f);
    const float np = fmaxf(norms[ip], 1e-6f);
    const float nn = fmaxf(norms[inn], 1e-6f);
    const float c = dp / (na * np) - dn / (na * nn) + 0.1f;
    cosv[r] = fmaxf(c, 0.f);
  }
}

// --------------------- kernel 4: mean (double accumulate) ------------------
__global__ __launch_bounds__(256) void reduce_kernel(const float* __restrict__ cosv,
                                                     float* __restrict__ out) {
  __shared__ double sh[4];
  double s = 0.0;
  for (int j = threadIdx.x; j < B_ROWS; j += 256) s += (double)cosv[j];
  for (int o = 32; o > 0; o >>= 1) s += __shfl_down(s, o, 64);
  const int wave = threadIdx.x >> 6, lane = threadIdx.x & 63;
  if (lane == 0) sh[wave] = s;
  __syncthreads();
  if (threadIdx.x == 0) {
    const double t = sh[0] + sh[1] + sh[2] + sh[3];
    out[0] = (float)(t / (double)B_ROWS);
  }
}

extern "C" void kernel_launch(void* const* d_in, const int* in_sizes, int n_in,
                              void* d_out, int out_size, void* d_ws, size_t ws_size,
                              hipStream_t stream) {
  const float* pred  = (const float*)d_in[0];
  const int* labels  = (const int*)d_in[1];
  float* out = (float*)d_out;

  char* ws = (char*)d_ws;
  float* norms  = (float*)(ws + 0);
  int*   idxp   = (int*)(ws + 32 * 1024);
  int*   idxn   = (int*)(ws + 64 * 1024);
  float* cosv   = (float*)(ws + 96 * 1024);
  int*   perm   = (int*)(ws + 128 * 1024);
  int*   gstart = (int*)(ws + 160 * 1024);

  norms_sort_kernel<<<B_ROWS / 4, 256, 0, stream>>>(pred, labels, norms, perm, gstart);
  argmax_kernel<<<B_ROWS / 8, 256, 0, stream>>>(labels, perm, gstart, idxp, idxn);
  cos_kernel<<<B_ROWS / 4, 256, 0, stream>>>(pred, norms, idxp, idxn, cosv);
  reduce_kernel<<<1, 256, 0, stream>>>(cosv, out);
}